// Round 2
// baseline (256.031 us; speedup 1.0000x reference)
//
#include <hip/hip_runtime.h>
#include <hip/hip_bf16.h>
#include <stdint.h>

#define D_IN   128
#define NPOLY  8256           // D*(D+1)/2
#define KDIM   8384           // D + NPOLY
#define B_ROWS 8192
#define N_COLS 512

// ---- workspace layout (bytes) ----
#define TBL_OFF   0
#define TBL_BYTES (NPOLY * 2)                         // 16512 (16-div)
#define WBF_OFF   (TBL_OFF + TBL_BYTES)
#define WBF_BYTES ((size_t)N_COLS * KDIM * 2)         // 8,585,216
#define FEA_OFF   (WBF_OFF + WBF_BYTES)
#define FEA_BYTES ((size_t)B_ROWS * KDIM * 2)         // 137,363,456
#define WS_NEED   (FEA_OFF + FEA_BYTES)               // ~146 MB

typedef __attribute__((ext_vector_type(8))) short    bf16x8_t;
typedef __attribute__((ext_vector_type(8))) uint16_t u16x8_t;
typedef __attribute__((ext_vector_type(8))) float    f32x8_t;
typedef __attribute__((ext_vector_type(4))) float    f32x4_t;

__device__ __forceinline__ uint16_t f2bf(float f) {
  union { float f; uint32_t u; } c; c.f = f;
  uint32_t u = c.u;
  uint32_t r = (u + 0x7fffu + ((u >> 16) & 1u)) >> 16;   // RNE
  return (uint16_t)r;
}

__device__ __forceinline__ void async_load16(void* lds_dst, const void* g_src) {
  __builtin_amdgcn_global_load_lds(
      (const __attribute__((address_space(1))) void*)g_src,
      (__attribute__((address_space(3))) void*)lds_dst,
      16, 0, 0);
}

// ---------------- setup: pair index table (uint16: i<<8|j) ----------------
__global__ void build_table(uint16_t* __restrict__ tbl) {
  int p = blockIdx.x * 256 + threadIdx.x;
  if (p >= NPOLY) return;
  float t = 66049.0f - 8.0f * (float)p;     // 257^2 - 8p
  int i = (int)((257.0f - sqrtf(t)) * 0.5f);
  if (i < 0) i = 0; if (i > 127) i = 127;
  while (i < 127 && ((i + 1) * (257 - (i + 1))) / 2 <= p) ++i;
  while (i > 0 && (i * (257 - i)) / 2 > p) --i;
  int j = i + (p - (i * (257 - i)) / 2);
  tbl[p] = (uint16_t)((i << 8) | j);
}

// ---------------- W f32 -> bf16, 8 elems/thread ----------------
__global__ void wconv(const float* __restrict__ w, uint16_t* __restrict__ wb) {
  int g = blockIdx.x * 256 + threadIdx.x;           // group of 8
  if (g >= (N_COLS * KDIM) / 8) return;
  f32x8_t v = *(const f32x8_t*)(w + (size_t)g * 8);
  bf16x8_t o;
#pragma unroll
  for (int e = 0; e < 8; ++e) o[e] = (short)f2bf(v[e]);
  *(bf16x8_t*)(wb + (size_t)g * 8) = o;
}

// ---------------- feature expansion -> bf16 feats [B_ROWS][KDIM] ----------------
// One row per block. 16B table load + LDS gathers + 16B bf16x8 store.
__global__ void feat_gen(const float* __restrict__ x, const uint16_t* __restrict__ tbl,
                         uint16_t* __restrict__ feats) {
  __shared__ float xs[D_IN];
  const int b = blockIdx.x;
  const int tid = threadIdx.x;
  if (tid < D_IN) xs[tid] = x[(size_t)b * D_IN + tid];
  __syncthreads();
  uint16_t* fr = feats + (size_t)b * KDIM;
  if (tid < D_IN / 8) {                      // head: x itself, 16 threads x 8
    bf16x8_t o;
#pragma unroll
    for (int e = 0; e < 8; ++e) o[e] = (short)f2bf(xs[tid * 8 + e]);
    *(bf16x8_t*)(fr + tid * 8) = o;
  }
  // poly: 1032 groups of 8
  for (int g = tid; g < NPOLY / 8; g += 256) {
    u16x8_t tt = *(const u16x8_t*)(tbl + g * 8);
    bf16x8_t o;
#pragma unroll
    for (int e = 0; e < 8; ++e) {
      uint32_t ij = tt[e];
      o[e] = (short)f2bf(xs[ij >> 8] * xs[ij & 255u]);
    }
    *(bf16x8_t*)(fr + D_IN + g * 8) = o;
  }
}

// ---------------- out init: bias broadcast, float4 ----------------
__global__ void init_out(float* __restrict__ out, const float* __restrict__ bias) {
  int idx = blockIdx.x * 256 + threadIdx.x;          // float4 index
  f32x4_t bv = *(const f32x4_t*)(bias + ((idx * 4) & (N_COLS - 1)));
  *(f32x4_t*)(out + (size_t)idx * 4) = bv;
}

// ---------------- bf16 MFMA GEMM: out += feats @ W^T ----------------
// BM=BN=128, BK=64, 4 waves (2x2), split-K=4 (4 blocks/CU), global_load_lds
// 16B staging with pre-swizzled source so ds_read_b128 is conflict-free.
#define BMT 128
#define BNT 128
#define BKT 64
#define KSTEPS 131   // 8384/64
#define KPART  33    // ceil(131/4)

__global__ __launch_bounds__(256, 4) void gemm_poly(
    const uint16_t* __restrict__ A,   // feats bf16 [B_ROWS][KDIM]
    const uint16_t* __restrict__ W,   // bf16 [N_COLS][KDIM]
    float* __restrict__ out) {
  __shared__ __align__(16) uint16_t sA[BMT * BKT];   // 16 KB
  __shared__ __align__(16) uint16_t sW[BNT * BKT];   // 16 KB

  const int tid  = threadIdx.x;
  const int lane = tid & 63;
  const int wv   = tid >> 6;
  const int wr   = wv >> 1;     // wave row (0..1)
  const int wc   = wv & 1;      // wave col (0..1)
  const int hi   = lane >> 4;   // 0..3
  const int lr   = lane & 15;

  const int b0 = blockIdx.x * BMT;
  const int n0 = blockIdx.y * BNT;
  const int kt0 = blockIdx.z * KPART;
  int kt1 = kt0 + KPART; if (kt1 > KSTEPS) kt1 = KSTEPS;

  // staging geometry: linear LDS offset L = q*4096 + tid*16 -> (row, cb)
  int rowq[4], cbxq[4];
#pragma unroll
  for (int q = 0; q < 4; ++q) {
    int L = q * 4096 + tid * 16;
    int row = L >> 7;          // 128 B per row
    int cb  = L & 127;
    rowq[q] = row;
    cbxq[q] = cb ^ ((row & 7) << 4);   // inverse-swizzled source chunk
  }

  // fragment LDS byte offsets (same XOR on read)
  int offA[4][2], offW[4][2];
#pragma unroll
  for (int f = 0; f < 4; ++f) {
    int rowA = wr * 64 + f * 16 + lr;
    int rowW = wc * 64 + f * 16 + lr;
#pragma unroll
    for (int kh = 0; kh < 2; ++kh) {
      int kb = kh * 64 + hi * 16;
      offA[f][kh] = rowA * 128 + (kb ^ ((rowA & 7) << 4));
      offW[f][kh] = rowW * 128 + (kb ^ ((rowW & 7) << 4));
    }
  }

  f32x4_t acc[4][4];
#pragma unroll
  for (int mf = 0; mf < 4; ++mf)
#pragma unroll
    for (int nf = 0; nf < 4; ++nf) {
      f32x4_t z = {0.f, 0.f, 0.f, 0.f};
      acc[mf][nf] = z;
    }

  const char* Ab = (const char*)A;
  const char* Wb = (const char*)W;

#define STAGE(kt)                                                              \
  {                                                                            \
    _Pragma("unroll")                                                          \
    for (int q = 0; q < 4; ++q) {                                              \
      const char* srcA =                                                       \
          Ab + ((size_t)(b0 + rowq[q]) * KDIM + (kt) * BKT) * 2 + cbxq[q];     \
      async_load16((char*)sA + q * 4096 + tid * 16, srcA);                     \
    }                                                                          \
    _Pragma("unroll")                                                          \
    for (int q = 0; q < 4; ++q) {                                              \
      const char* srcW =                                                       \
          Wb + ((size_t)(n0 + rowq[q]) * KDIM + (kt) * BKT) * 2 + cbxq[q];     \
      async_load16((char*)sW + q * 4096 + tid * 16, srcW);                     \
    }                                                                          \
  }

  STAGE(kt0);
  for (int kt = kt0; kt < kt1; ++kt) {
    __syncthreads();
    bf16x8_t a[4][2], b[4][2];
#pragma unroll
    for (int mf = 0; mf < 4; ++mf)
#pragma unroll
      for (int kh = 0; kh < 2; ++kh)
        a[mf][kh] = *(const bf16x8_t*)((const char*)sA + offA[mf][kh]);
#pragma unroll
    for (int nf = 0; nf < 4; ++nf)
#pragma unroll
      for (int kh = 0; kh < 2; ++kh)
        b[nf][kh] = *(const bf16x8_t*)((const char*)sW + offW[nf][kh]);
#pragma unroll
    for (int mf = 0; mf < 4; ++mf)
#pragma unroll
      for (int nf = 0; nf < 4; ++nf) {
        acc[mf][nf] = __builtin_amdgcn_mfma_f32_16x16x32_bf16(
            a[mf][0], b[nf][0], acc[mf][nf], 0, 0, 0);
        acc[mf][nf] = __builtin_amdgcn_mfma_f32_16x16x32_bf16(
            a[mf][1], b[nf][1], acc[mf][nf], 0, 0, 0);
      }
    __syncthreads();
    if (kt + 1 < kt1) STAGE(kt + 1);
  }

  // epilogue: C/D layout col=lane&15, row=(lane>>4)*4+reg
#pragma unroll
  for (int mf = 0; mf < 4; ++mf) {
    int row = b0 + wr * 64 + mf * 16 + hi * 4;
#pragma unroll
    for (int nf = 0; nf < 4; ++nf) {
      int col = n0 + wc * 64 + nf * 16 + lr;
#pragma unroll
      for (int r = 0; r < 4; ++r) {
        atomicAdd(&out[(size_t)(row + r) * N_COLS + col], acc[mf][nf][r]);
      }
    }
  }
#undef STAGE
}

// ---------------- naive fallback (only if ws too small) ----------------
__global__ void naive_poly(const float* __restrict__ x, const float* __restrict__ w,
                           const float* __restrict__ bias, float* __restrict__ out) {
  size_t o = (size_t)blockIdx.x * 256 + threadIdx.x;
  if (o >= (size_t)B_ROWS * N_COLS) return;
  int n = (int)(o >> 13);
  int b = (int)(o & (B_ROWS - 1));
  const float* xr = x + (size_t)b * D_IN;
  const float* wr = w + (size_t)n * KDIM;
  float acc = bias[n];
  for (int k = 0; k < D_IN; ++k) acc += wr[k] * xr[k];
  int p = D_IN;
  for (int i = 0; i < D_IN; ++i) {
    float xi = xr[i];
    for (int j = i; j < D_IN; ++j) acc += wr[p++] * xi * xr[j];
  }
  out[(size_t)b * N_COLS + n] = acc;
}

extern "C" void kernel_launch(void* const* d_in, const int* in_sizes, int n_in,
                              void* d_out, int out_size, void* d_ws, size_t ws_size,
                              hipStream_t stream) {
  const float* x    = (const float*)d_in[0];
  const float* w    = (const float*)d_in[1];
  const float* bias = (const float*)d_in[2];
  float* out = (float*)d_out;

  if (ws_size < WS_NEED) {   // safety net: correct but slow
    naive_poly<<<(B_ROWS * N_COLS) / 256, 256, 0, stream>>>(x, w, bias, out);
    return;
  }

  char* ws = (char*)d_ws;
  uint16_t* tbl = (uint16_t*)(ws + TBL_OFF);
  uint16_t* wb  = (uint16_t*)(ws + WBF_OFF);
  uint16_t* fe  = (uint16_t*)(ws + FEA_OFF);

  build_table<<<(NPOLY + 255) / 256, 256, 0, stream>>>(tbl);
  wconv<<<(N_COLS * KDIM / 8 + 255) / 256, 256, 0, stream>>>(w, wb);
  feat_gen<<<B_ROWS, 256, 0, stream>>>(x, tbl, fe);
  init_out<<<(B_ROWS * N_COLS / 4) / 256, 256, 0, stream>>>(out, bias);
  gemm_poly<<<dim3(B_ROWS / BMT, N_COLS / BNT, 4), 256, 0, stream>>>(fe, wb, out);
}

// Round 3
// 201.421 us; speedup vs baseline: 1.2711x; 1.2711x over previous
//
#include <hip/hip_runtime.h>
#include <hip/hip_bf16.h>
#include <stdint.h>

#define D_IN   128
#define NPOLY  8256           // D*(D+1)/2
#define KDIM   8384           // D + NPOLY
#define B_ROWS 8192
#define N_COLS 512

// ---- workspace layout (bytes) ----
#define TBL_OFF   0
#define TBL_BYTES (NPOLY * 2)                         // 16512 (16-div)
#define WBF_OFF   (TBL_OFF + TBL_BYTES)
#define WBF_BYTES ((size_t)N_COLS * KDIM * 2)         // 8,585,216
#define FEA_OFF   (WBF_OFF + WBF_BYTES)
#define FEA_BYTES ((size_t)B_ROWS * KDIM * 2)         // 137,363,456
#define WS_NEED   (FEA_OFF + FEA_BYTES)               // ~146 MB

typedef __attribute__((ext_vector_type(8))) short    bf16x8_t;
typedef __attribute__((ext_vector_type(8))) float    f32x8_t;
typedef __attribute__((ext_vector_type(4))) float    f32x4_t;

__device__ __forceinline__ uint16_t f2bf(float f) {
  union { float f; uint32_t u; } c; c.f = f;
  uint32_t u = c.u;
  uint32_t r = (u + 0x7fffu + ((u >> 16) & 1u)) >> 16;   // RNE
  return (uint16_t)r;
}

__device__ __forceinline__ void async_load16(void* lds_dst, const void* g_src) {
  __builtin_amdgcn_global_load_lds(
      (const __attribute__((address_space(1))) void*)g_src,
      (__attribute__((address_space(3))) void*)lds_dst,
      16, 0, 0);
}

// ---------------- setup: pair index table (uint16: i<<8|j) ----------------
__global__ void build_table(uint16_t* __restrict__ tbl) {
  int p = blockIdx.x * 256 + threadIdx.x;
  if (p >= NPOLY) return;
  float t = 66049.0f - 8.0f * (float)p;     // 257^2 - 8p
  int i = (int)((257.0f - sqrtf(t)) * 0.5f);
  if (i < 0) i = 0; if (i > 127) i = 127;
  while (i < 127 && ((i + 1) * (257 - (i + 1))) / 2 <= p) ++i;
  while (i > 0 && (i * (257 - i)) / 2 > p) --i;
  int j = i + (p - (i * (257 - i)) / 2);
  tbl[p] = (uint16_t)((i << 8) | j);
}

// ---------------- W f32 -> bf16, 8 elems/thread ----------------
__global__ void wconv(const float* __restrict__ w, uint16_t* __restrict__ wb) {
  int g = blockIdx.x * 256 + threadIdx.x;           // group of 8
  if (g >= (N_COLS * KDIM) / 8) return;
  f32x8_t v = *(const f32x8_t*)(w + (size_t)g * 8);
  bf16x8_t o;
#pragma unroll
  for (int e = 0; e < 8; ++e) o[e] = (short)f2bf(v[e]);
  *(bf16x8_t*)(wb + (size_t)g * 8) = o;
}

// ---------------- feature expansion -> bf16 feats [B_ROWS][KDIM] ----------------
// One row per block. Conflict-free: thread t computes p = t, t+256, ... so
// consecutive lanes read consecutive xs[j] (stride-1, 2-way = free) and
// wave-uniform xs[i] (broadcast). Products staged in LDS (consecutive u16
// writes = free), then one b128-vectorized copy to global.
__global__ __launch_bounds__(256) void feat_gen(
    const float* __restrict__ x, const uint16_t* __restrict__ tbl,
    uint16_t* __restrict__ feats) {
  __shared__ float xs[D_IN];
  __shared__ __align__(16) uint16_t pr[KDIM];        // 16768 B staging
  const int b = blockIdx.x;
  const int tid = threadIdx.x;
  if (tid < D_IN) {
    float v = x[(size_t)b * D_IN + tid];
    xs[tid] = v;
    pr[tid] = f2bf(v);
  }
  __syncthreads();
#pragma unroll 4
  for (int p = tid; p < NPOLY; p += 256) {
    uint32_t t = tbl[p];
    pr[D_IN + p] = f2bf(xs[t >> 8] * xs[t & 255u]);
  }
  __syncthreads();
  const bf16x8_t* src = (const bf16x8_t*)pr;
  bf16x8_t* dst = (bf16x8_t*)(feats + (size_t)b * KDIM);
  for (int g = tid; g < KDIM / 8; g += 256) dst[g] = src[g];
}

// ---------------- out init: bias broadcast, float4 ----------------
__global__ void init_out(float* __restrict__ out, const float* __restrict__ bias) {
  int idx = blockIdx.x * 256 + threadIdx.x;          // float4 index
  f32x4_t bv = *(const f32x4_t*)(bias + ((idx * 4) & (N_COLS - 1)));
  *(f32x4_t*)(out + (size_t)idx * 4) = bv;
}

// ---------------- bf16 MFMA GEMM: out += feats @ W^T ----------------
// BM=BN=128, BK=64, 4 waves (2x2), split-K=2. Double-buffered LDS with
// EARLY staging: next K-tile's global_load_lds issued before the current
// tile's ds_read+MFMA, one barrier per K-step -> load latency overlaps
// compute. Pre-swizzled source (XOR st-16) keeps ds_read_b128 conflict-free.
#define BMT 128
#define BNT 128
#define BKT 64
#define KSTEPS 131   // 8384/64
#define KCUT 66      // split: [0,66) and [66,131)

__global__ __launch_bounds__(256, 2) void gemm_poly(
    const uint16_t* __restrict__ A,   // feats bf16 [B_ROWS][KDIM]
    const uint16_t* __restrict__ W,   // bf16 [N_COLS][KDIM]
    float* __restrict__ out) {
  __shared__ __align__(16) uint16_t sA[2][BMT * BKT];   // 2 x 16 KB
  __shared__ __align__(16) uint16_t sW[2][BNT * BKT];   // 2 x 16 KB

  const int tid  = threadIdx.x;
  const int lane = tid & 63;
  const int wv   = tid >> 6;
  const int wr   = wv >> 1;     // wave row (0..1)
  const int wc   = wv & 1;      // wave col (0..1)
  const int hi   = lane >> 4;   // 0..3
  const int lr   = lane & 15;

  const int b0 = blockIdx.x * BMT;
  const int n0 = blockIdx.y * BNT;
  const int kt0 = (blockIdx.z == 0) ? 0 : KCUT;
  const int kt1 = (blockIdx.z == 0) ? KCUT : KSTEPS;

  // staging geometry: linear LDS offset L = q*4096 + tid*16 -> (row, cb)
  int rowq[4], cbxq[4];
#pragma unroll
  for (int q = 0; q < 4; ++q) {
    int L = q * 4096 + tid * 16;
    int row = L >> 7;          // 128 B per row
    int cb  = L & 127;
    rowq[q] = row;
    cbxq[q] = cb ^ ((row & 7) << 4);   // inverse-swizzled source chunk
  }

  // fragment LDS byte offsets within one buffer (same XOR on read)
  int offA[4][2], offW[4][2];
#pragma unroll
  for (int f = 0; f < 4; ++f) {
    int rowA = wr * 64 + f * 16 + lr;
    int rowW = wc * 64 + f * 16 + lr;
#pragma unroll
    for (int kh = 0; kh < 2; ++kh) {
      int kb = kh * 64 + hi * 16;
      offA[f][kh] = rowA * 128 + (kb ^ ((rowA & 7) << 4));
      offW[f][kh] = rowW * 128 + (kb ^ ((rowW & 7) << 4));
    }
  }

  f32x4_t acc[4][4];
#pragma unroll
  for (int mf = 0; mf < 4; ++mf)
#pragma unroll
    for (int nf = 0; nf < 4; ++nf) {
      f32x4_t z = {0.f, 0.f, 0.f, 0.f};
      acc[mf][nf] = z;
    }

  const char* Ab = (const char*)A;
  const char* Wb = (const char*)W;

#define STAGE(buf, kt)                                                         \
  {                                                                            \
    _Pragma("unroll")                                                          \
    for (int q = 0; q < 4; ++q) {                                              \
      const char* srcA =                                                       \
          Ab + ((size_t)(b0 + rowq[q]) * KDIM + (kt) * BKT) * 2 + cbxq[q];     \
      async_load16((char*)sA[buf] + q * 4096 + tid * 16, srcA);                \
    }                                                                          \
    _Pragma("unroll")                                                          \
    for (int q = 0; q < 4; ++q) {                                              \
      const char* srcW =                                                       \
          Wb + ((size_t)(n0 + rowq[q]) * KDIM + (kt) * BKT) * 2 + cbxq[q];     \
      async_load16((char*)sW[buf] + q * 4096 + tid * 16, srcW);                \
    }                                                                          \
  }

  STAGE(0, kt0);
  __syncthreads();                 // drain prologue staging
  int cur = 0;
  for (int kt = kt0; kt < kt1; ++kt) {
    if (kt + 1 < kt1) STAGE(cur ^ 1, kt + 1);   // EARLY: overlaps with below
    bf16x8_t a[4][2], b[4][2];
#pragma unroll
    for (int mf = 0; mf < 4; ++mf)
#pragma unroll
      for (int kh = 0; kh < 2; ++kh)
        a[mf][kh] = *(const bf16x8_t*)((const char*)sA[cur] + offA[mf][kh]);
#pragma unroll
    for (int nf = 0; nf < 4; ++nf)
#pragma unroll
      for (int kh = 0; kh < 2; ++kh)
        b[nf][kh] = *(const bf16x8_t*)((const char*)sW[cur] + offW[nf][kh]);
    __builtin_amdgcn_s_setprio(1);
#pragma unroll
    for (int mf = 0; mf < 4; ++mf)
#pragma unroll
      for (int nf = 0; nf < 4; ++nf) {
        acc[mf][nf] = __builtin_amdgcn_mfma_f32_16x16x32_bf16(
            a[mf][0], b[nf][0], acc[mf][nf], 0, 0, 0);
        acc[mf][nf] = __builtin_amdgcn_mfma_f32_16x16x32_bf16(
            a[mf][1], b[nf][1], acc[mf][nf], 0, 0, 0);
      }
    __builtin_amdgcn_s_setprio(0);
    __syncthreads();               // drains vm+lgkm: next buffer ready,
    cur ^= 1;                      // prev buffer free for overwrite
  }

  // epilogue: C/D layout col=lane&15, row=(lane>>4)*4+reg
#pragma unroll
  for (int mf = 0; mf < 4; ++mf) {
    int row = b0 + wr * 64 + mf * 16 + hi * 4;
#pragma unroll
    for (int nf = 0; nf < 4; ++nf) {
      int col = n0 + wc * 64 + nf * 16 + lr;
#pragma unroll
      for (int r = 0; r < 4; ++r) {
        atomicAdd(&out[(size_t)(row + r) * N_COLS + col], acc[mf][nf][r]);
      }
    }
  }
#undef STAGE
}

// ---------------- naive fallback (only if ws too small) ----------------
__global__ void naive_poly(const float* __restrict__ x, const float* __restrict__ w,
                           const float* __restrict__ bias, float* __restrict__ out) {
  size_t o = (size_t)blockIdx.x * 256 + threadIdx.x;
  if (o >= (size_t)B_ROWS * N_COLS) return;
  int n = (int)(o >> 13);
  int b = (int)(o & (B_ROWS - 1));
  const float* xr = x + (size_t)b * D_IN;
  const float* wr = w + (size_t)n * KDIM;
  float acc = bias[n];
  for (int k = 0; k < D_IN; ++k) acc += wr[k] * xr[k];
  int p = D_IN;
  for (int i = 0; i < D_IN; ++i) {
    float xi = xr[i];
    for (int j = i; j < D_IN; ++j) acc += wr[p++] * xi * xr[j];
  }
  out[(size_t)b * N_COLS + n] = acc;
}

extern "C" void kernel_launch(void* const* d_in, const int* in_sizes, int n_in,
                              void* d_out, int out_size, void* d_ws, size_t ws_size,
                              hipStream_t stream) {
  const float* x    = (const float*)d_in[0];
  const float* w    = (const float*)d_in[1];
  const float* bias = (const float*)d_in[2];
  float* out = (float*)d_out;

  if (ws_size < WS_NEED) {   // safety net: correct but slow
    naive_poly<<<(B_ROWS * N_COLS) / 256, 256, 0, stream>>>(x, w, bias, out);
    return;
  }

  char* ws = (char*)d_ws;
  uint16_t* tbl = (uint16_t*)(ws + TBL_OFF);
  uint16_t* wb  = (uint16_t*)(ws + WBF_OFF);
  uint16_t* fe  = (uint16_t*)(ws + FEA_OFF);

  build_table<<<(NPOLY + 255) / 256, 256, 0, stream>>>(tbl);
  wconv<<<(N_COLS * KDIM / 8 + 255) / 256, 256, 0, stream>>>(w, wb);
  feat_gen<<<B_ROWS, 256, 0, stream>>>(x, tbl, fe);
  init_out<<<(B_ROWS * N_COLS / 4) / 256, 256, 0, stream>>>(out, bias);
  gemm_poly<<<dim3(B_ROWS / BMT, N_COLS / BNT, 2), 256, 0, stream>>>(fe, wb, out);
}